// Round 10
// baseline (78.539 us; speedup 1.0000x reference)
//
#include <hip/hip_runtime.h>

#define B_TOTAL 131072
#define NF 32
#define NA 8
#define NH 64

using frag_ab = __attribute__((ext_vector_type(8))) short;   // 8 bf16 (4 VGPRs)
using f32x16  = __attribute__((ext_vector_type(16))) float;  // 32x32 accumulator
typedef int   v2i __attribute__((ext_vector_type(2)));
typedef float v2f __attribute__((ext_vector_type(2)));

__device__ __forceinline__ unsigned short f2bf(float x) {
  unsigned u = __float_as_uint(x);
  u = (u + 0x7FFFu + ((u >> 16) & 1u)) >> 16;   // RNE
  return (unsigned short)u;
}

// 32x32 A-frag pack (R5/R6/R9-verified, UNCHANGED)
__global__ void pack_w1_kernel(const float* __restrict__ W1, const float* __restrict__ b1,
                               unsigned short* __restrict__ w1p) {
  int idx = blockIdx.x * 256 + threadIdx.x;   // 98304 total
  int j = idx & 7, l = (idx >> 3) & 63, tq = idx >> 9;
  int q = tq % 6, f = tq / 6;
  int ht = q / 3, kt = q % 3;
  int h = ht * 32 + (l & 31);
  int i = kt * 16 + ((l >> 5) << 3) + j;
  float v = 0.0f;
  if (i < NF + NA)       v = W1[(f * (NF + NA) + i) * NH + h];
  else if (i == NF + NA) v = b1[f * NH + h];
  w1p[idx] = f2bf(v);
}

// R5/R9-verified (UNCHANGED): w2p[((f*2+g)*2+ht)*16 + r] = W2[f][ht*32 + (r&3) + 8*(r>>2) + 4*g]
__global__ void pack_w2_kernel(const float* __restrict__ W2, float* __restrict__ w2p) {
  int idx = blockIdx.x * 256 + threadIdx.x;   // 4096 total
  int r = idx & 15, ht = (idx >> 4) & 1, g = (idx >> 5) & 1, f = idx >> 6;
  w2p[idx] = W2[f * NH + ht * 32 + (r & 3) + 8 * (r >> 2) + 4 * g];
}

// fa fragments precomputed ONCE (formula = R9's verified in-kernel builder):
// fa2[((bt*3+kt)*64 + l)*8 + j]:  b = bt*32 + (l&31), g = l>>5
//   kt<2 -> bf16(ft[b][kt*16+g*8+j]); kt=2,g=0 -> bf16(at[b][j]); kt=2,g=1 -> (j==0)?1.0:0
__global__ void build_fa2_kernel(const float* __restrict__ ft, const float* __restrict__ at,
                                 unsigned short* __restrict__ fa2) {
  int idx = blockIdx.x * 256 + threadIdx.x;   // (B/32)*3*64*8 = 6291456
  int j = idx & 7;
  int l = (idx >> 3) & 63;
  int rest = idx >> 9;
  int kt = rest % 3;
  long bt = rest / 3;
  int g = l >> 5, lc = l & 31;
  long b = bt * 32 + lc;
  unsigned short o;
  if (kt < 2)       o = f2bf(ft[b * NF + kt * 16 + g * 8 + j]);
  else if (g == 0)  o = f2bf(at[b * NA + j]);
  else              o = (j == 0) ? (unsigned short)0x3F80 : (unsigned short)0;
  fa2[idx] = o;
}

__device__ __forceinline__ v2f pk_fma(v2f a, v2f b, v2f c) {   // R5/R6/R9-verified
  v2f d;
  asm("v_pk_fma_f32 %0, %1, %2, %3" : "=v"(d) : "v"(a), "v"(b), "v"(c));
  return d;
}

__device__ __forceinline__ float xor32_add(float v) {   // R4/R5/R6/R9-verified
  v2i p = __builtin_amdgcn_permlane32_swap(__float_as_int(v), __float_as_int(v), false, false);
  return __int_as_float(p.x) + __int_as_float(p.y);
}

// f-outer, zero-LDS, zero-barrier; fa frags pre-packed; 1-deep prefetch; full unroll.
__global__ __launch_bounds__(256, 3) void fused_mlp_kernel(
    const unsigned short* __restrict__ fa2, const unsigned short* __restrict__ w1p,
    const float* __restrict__ w2p, float* __restrict__ ws) {
  const int t = threadIdx.x;
  const int wv = t >> 6;
  const int l = t & 63;
  const int g = l >> 5;
  const int lc = l & 31;
  const int gf = blockIdx.x >> 7;        // f-pair 0..15
  const int nb = blockIdx.x & 127;       // b-range; XCD = nb%8 for all gf -> fa2 L2 reuse

  // ---- W1 frags -> registers, ONCE (48 VGPR) ----
  frag_ab wf[2][2][3];
#pragma unroll
  for (int f2 = 0; f2 < 2; ++f2)
#pragma unroll
    for (int ht = 0; ht < 2; ++ht)
#pragma unroll
      for (int kt = 0; kt < 3; ++kt)
        wf[f2][ht][kt] = *(const frag_ab*)(w1p + ((((gf * 2 + f2) * 6 + ht * 3 + kt) * 64 + l) * 8));

  const f32x16 zero16 = {0.f,0.f,0.f,0.f,0.f,0.f,0.f,0.f,0.f,0.f,0.f,0.f,0.f,0.f,0.f,0.f};
  const long bt0 = (long)nb * 32 + wv * 8;   // this wave's first b-tile

  frag_ab cur[3], nxt[3];
#pragma unroll
  for (int kt = 0; kt < 3; ++kt)
    cur[kt] = *(const frag_ab*)(fa2 + ((bt0 * 3 + kt) * 64 + l) * 8);

#pragma unroll
  for (int it = 0; it < 8; ++it) {
    if (it < 7) {   // prefetch next iteration's frags (latency hides under compute)
#pragma unroll
      for (int kt = 0; kt < 3; ++kt)
        nxt[kt] = *(const frag_ab*)(fa2 + (((bt0 + it + 1) * 3 + kt) * 64 + l) * 8);
    }

    float resv[2];
#pragma unroll
    for (int f2 = 0; f2 < 2; ++f2) {
      f32x16 a0 = zero16, a1 = zero16;
#pragma unroll
      for (int kt = 0; kt < 3; ++kt) {
        a0 = __builtin_amdgcn_mfma_f32_32x32x16_bf16(wf[f2][0][kt], cur[kt], a0, 0, 0, 0);
        a1 = __builtin_amdgcn_mfma_f32_32x32x16_bf16(wf[f2][1][kt], cur[kt], a1, 0, 0, 0);
      }
      // layer 2 (R9-verbatim): relu + dot(W2); W2 from L1 per use (saves 64 VGPR)
      const float4* wp2 = (const float4*)w2p + ((gf * 2 + f2) * 2 + g) * 8;
      v2f ps0 = {0.f, 0.f}, ps1 = {0.f, 0.f};
#pragma unroll
      for (int rq = 0; rq < 4; ++rq) {
        float4 w0 = wp2[rq], w1 = wp2[4 + rq];
        v2f m;
        m[0] = fmaxf(a0[rq * 4 + 0], 0.f); m[1] = fmaxf(a0[rq * 4 + 1], 0.f);
        ps0 = pk_fma(m, (v2f){w0.x, w0.y}, ps0);
        m[0] = fmaxf(a0[rq * 4 + 2], 0.f); m[1] = fmaxf(a0[rq * 4 + 3], 0.f);
        ps0 = pk_fma(m, (v2f){w0.z, w0.w}, ps0);
        m[0] = fmaxf(a1[rq * 4 + 0], 0.f); m[1] = fmaxf(a1[rq * 4 + 1], 0.f);
        ps1 = pk_fma(m, (v2f){w1.x, w1.y}, ps1);
        m[0] = fmaxf(a1[rq * 4 + 2], 0.f); m[1] = fmaxf(a1[rq * 4 + 3], 0.f);
        ps1 = pk_fma(m, (v2f){w1.z, w1.w}, ps1);
      }
      float s = (ps0[0] + ps0[1]) + (ps1[0] + ps1[1]);
      resv[f2] = xor32_add(s);
    }

    // block-private contiguous slice (no cross-block lines)
    if (g == 0) {
      const long b = (bt0 + it) * 32 + lc;
      float2 o; o.x = resv[0]; o.y = resv[1];
      *(float2*)(ws + ((long)gf * B_TOTAL + b) * 2) = o;
    }

#pragma unroll
    for (int kt = 0; kt < 3; ++kt) cur[kt] = nxt[kt];
  }
}

// R9-verified (UNCHANGED): out[b][f] = ws[f>>1][b][f&1] + b2[f] + ft[b][f]
__global__ void add_kernel(const float* __restrict__ ws, const float* __restrict__ ft,
                           const float* __restrict__ b2, float* __restrict__ out) {
  int flat = blockIdx.x * 256 + threadIdx.x;   // B*8 total
  int f4 = flat & 7;
  long b = flat >> 3;
  const float2* s0 = (const float2*)ws + (long)(2 * f4) * B_TOTAL + b;
  const float2* s1 = (const float2*)ws + (long)(2 * f4 + 1) * B_TOTAL + b;
  float2 v0 = *s0, v1 = *s1;
  float4 x  = *(const float4*)(ft + b * NF + f4 * 4);
  float4 bb = *(const float4*)(b2 + f4 * 4);
  float4 o;
  o.x = v0.x + bb.x + x.x;
  o.y = v0.y + bb.y + x.y;
  o.z = v1.x + bb.z + x.z;
  o.w = v1.y + bb.w + x.w;
  *(float4*)(out + b * NF + f4 * 4) = o;
}

extern "C" void kernel_launch(void* const* d_in, const int* in_sizes, int n_in,
                              void* d_out, int out_size, void* d_ws, size_t ws_size,
                              hipStream_t stream) {
  const float* ft = (const float*)d_in[0];
  const float* at = (const float*)d_in[1];
  const float* W1 = (const float*)d_in[2];
  const float* b1 = (const float*)d_in[3];
  const float* W2 = (const float*)d_in[4];
  const float* b2 = (const float*)d_in[5];
  float* out = (float*)d_out;

  unsigned short* w1p = (unsigned short*)d_ws;                       // 192 KB
  float* w2p = (float*)((char*)d_ws + (1u << 18));                   // 16 KB  @ 256 KB
  unsigned short* fa2 = (unsigned short*)((char*)d_ws + (1u << 19)); // 12.6 MB @ 512 KB
  float* ws  = (float*)((char*)d_ws + (14u << 20));                  // 16.7 MB @ 14 MB

  pack_w1_kernel<<<384, 256, 0, stream>>>(W1, b1, w1p);
  pack_w2_kernel<<<16, 256, 0, stream>>>(W2, w2p);
  build_fa2_kernel<<<24576, 256, 0, stream>>>(ft, at, fa2);
  fused_mlp_kernel<<<2048, 256, 0, stream>>>(fa2, w1p, w2p, ws);
  add_kernel<<<B_TOTAL * 8 / 256, 256, 0, stream>>>(ws, ft, b2, out);
}